// Round 13
// baseline (759.016 us; speedup 1.0000x reference)
//
#include <hip/hip_runtime.h>
#include <math.h>

// Gated delta-rule linear attention (Qwen3.5 GatedDeltaNet).
// Phase A (512 thr): MFMA-based M/attn (f16 h/l 3-product); f32x4-vectorized
//   forward substitution; wave-split epilogue (waves 0-3 solve+KC/VC, 4-7 emit).
// Phase B: 4 blocks per bh x 2 waves (128 CUs); shared-LDS staging, 4-phase
//   pipeline (raw s_barrier + exact counted vmcnt), LDS-bounce C->B
//   redistribution; gl prefetched a chunk ahead; out-stores issued at end of
//   chunk so no vmcnt wait depends on store retirement.

namespace {
constexpr int Bn = 2, Sn = 4096, Hn = 16, DKn = 128, DVn = 128, Cn = 64, Nn = 64;
// per-chunk ws bytes: KC h/l @0/16384, QG @32768/49152, KD @65536/81920,
// AT(6 nonzero tiles) h @98304 l @104448, VC f32 @110592 (32K) => 140KB
constexpr long CHUNK_B = 143360;
constexpr long PER_BH_B = (long)Nn * CHUNK_B + Nn * 4;   // + GL floats
}

typedef __attribute__((ext_vector_type(4))) float f32x4;
typedef __attribute__((ext_vector_type(8))) _Float16 f16x8;
typedef __attribute__((ext_vector_type(4))) _Float16 f16x4;

__device__ __forceinline__ void fsplit(float x, _Float16& h, _Float16& l) {
  h = (_Float16)x;
  l = (_Float16)(x - (float)h);
}

__device__ __forceinline__ void gl_lds16(const void* g, void* l) {
  __builtin_amdgcn_global_load_lds(
      (const __attribute__((address_space(1))) void*)g,
      (__attribute__((address_space(3))) void*)l, 16, 0, 0);
}

#define MFMA16(D, A, B) D = __builtin_amdgcn_mfma_f32_16x16x32_f16(A, B, D, 0, 0, 0)

// f16 LDS [64][128], 8-elem granules XOR-swizzled by row&7
__device__ __forceinline__ int sidx(int r, int dk) {
  return r * 128 + (((dk >> 3) ^ (r & 7)) << 3) + (dk & 7);
}

__global__ __launch_bounds__(512, 1) void gdn_phaseA(
    const float* __restrict__ q, const float* __restrict__ k,
    const float* __restrict__ v, const float* __restrict__ g,
    const float* __restrict__ beta, char* __restrict__ wsb,
    int bh0, long ncp)
{
  __shared__ __align__(16) _Float16 sAh[8192], sAl[8192];   // k norm h/l
  __shared__ __align__(16) _Float16 sQh[8192], sQl[8192];   // q norm*scale h/l
  __shared__ __align__(16) float sM[64][68];                // strict-lower M (16B rows)
  __shared__ __align__(16) float satt[4096];                // attn, swizzled
  __shared__ __align__(16) float sV[64 * 132];              // v chunk
  __shared__ float s_gc[64], s_egc[64], s_inv[64], s_ekd[64], s_beta[64];

  const int t    = threadIdx.x;
  const int lane = t & 63;
  const int w    = t >> 6;
  const int pl = blockIdx.x;
  const int p  = bh0 * Nn + pl;
  const int n  = p % Nn;
  const int bhx = p / Nn;
  const int hh_ = bhx % Hn;
  const int bb_ = bhx / Hn;
  const long base   = (((long)bb_ * Sn + (long)n * Cn) * Hn + hh_) * DKn;
  const long rowstr = (long)Hn * DKn;                    // 2048
  const long gbase  = ((long)bb_ * Sn + (long)n * Cn) * Hn + hh_;
  const long cb     = (long)pl * CHUNK_B;

  // ---- stage v chunk into sV (coalesced) ----
  #pragma unroll
  for (int i = 0; i < 4; ++i) {
    int idx = t + 512 * i;
    int r = idx >> 5, c4 = (idx & 31) << 2;
    *(f32x4*)&sV[r * 132 + c4] = *(const f32x4*)(v + base + (long)r * rowstr + c4);
  }

  // ---- smalls + wave-parallel scan (wave 0) ----
  if (t < 64) {
    s_beta[t] = beta[gbase + (long)t * Hn];
    float x = g[gbase + (long)t * Hn];
    #pragma unroll
    for (int s = 1; s < 64; s <<= 1) {
      float y = __shfl_up(x, s, 64);
      if (t >= s) x += y;
    }
    s_gc[t]  = x;
    float eg = expf(x);
    s_egc[t] = eg;
    s_inv[t] = expf(-x);
    float g63 = __shfl(x, 63, 64);
    s_ekd[t] = expf(g63 - x);
    if (t == 63) ((float*)(wsb + ncp * CHUNK_B))[pl] = eg;   // GL = exp(gc[63])
  }

  // ---- q/k load + l2norm (8 thr/row) + f16 split to swizzled LDS ----
  {
    const int r = t >> 3, sub = t & 7;
    f32x4 ka[4], qa[4];
    #pragma unroll
    for (int i = 0; i < 4; ++i) {
      ka[i] = *(const f32x4*)(k + base + (long)r * rowstr + sub * 16 + 4 * i);
      qa[i] = *(const f32x4*)(q + base + (long)r * rowstr + sub * 16 + 4 * i);
    }
    float sk = 0.f, sq = 0.f;
    #pragma unroll
    for (int i = 0; i < 4; ++i) {
      sk += ka[i][0]*ka[i][0] + ka[i][1]*ka[i][1] + ka[i][2]*ka[i][2] + ka[i][3]*ka[i][3];
      sq += qa[i][0]*qa[i][0] + qa[i][1]*qa[i][1] + qa[i][2]*qa[i][2] + qa[i][3]*qa[i][3];
    }
    sk += __shfl_xor(sk, 1, 64); sk += __shfl_xor(sk, 2, 64); sk += __shfl_xor(sk, 4, 64);
    sq += __shfl_xor(sq, 1, 64); sq += __shfl_xor(sq, 2, 64); sq += __shfl_xor(sq, 4, 64);
    const float rk = rsqrtf(sk + 1e-6f);
    const float rq = rsqrtf(sq + 1e-6f) * 0.08838834764831845f;  // * Dk^-0.5
    #pragma unroll
    for (int i = 0; i < 4; ++i) {
      const int dk0 = sub * 16 + 4 * i;
      const int go = sidx(r, dk0);
      f16x4 h4, l4, qh4, ql4;
      #pragma unroll
      for (int e = 0; e < 4; ++e) {
        _Float16 h_, l_;
        fsplit(ka[i][e] * rk, h_, l_); h4[e] = h_; l4[e] = l_;
        fsplit(qa[i][e] * rq, h_, l_); qh4[e] = h_; ql4[e] = l_;
      }
      *(f16x4*)&sAh[go] = h4;  *(f16x4*)&sAl[go] = l4;
      *(f16x4*)&sQh[go] = qh4; *(f16x4*)&sQl[go] = ql4;
    }
  }
  __syncthreads();

  // ---- MFMA: kkT (symmetric operand) and attT = k·qT; epilogues ----
  {
    const int mt  = w & 3;          // row-tile (r for kkT, d for att)
    const int tc0 = (w >> 2) * 2;   // col-tile base (2 tiles per wave)
    const f32x4 zero = {0.f, 0.f, 0.f, 0.f};
    f32x4 mk0 = zero, mk1 = zero, ma0 = zero, ma1 = zero;
    #pragma unroll
    for (int kt = 0; kt < 4; ++kt) {
      const int rA = mt * 16 + (lane & 15);
      const int gA = rA * 128 + (((kt * 4 + (lane >> 4)) ^ (rA & 7)) << 3);
      f16x8 fa_h = *(const f16x8*)&sAh[gA];
      f16x8 fa_l = *(const f16x8*)&sAl[gA];
      #pragma unroll
      for (int j = 0; j < 2; ++j) {
        const int rB = (tc0 + j) * 16 + (lane & 15);
        const int gB = rB * 128 + (((kt * 4 + (lane >> 4)) ^ (rB & 7)) << 3);
        f16x8 fb_h = *(const f16x8*)&sAh[gB];
        f16x8 fb_l = *(const f16x8*)&sAl[gB];
        f16x8 fq_h = *(const f16x8*)&sQh[gB];
        f16x8 fq_l = *(const f16x8*)&sQl[gB];
        if (j == 0) {
          MFMA16(mk0, fa_h, fb_h); MFMA16(mk0, fa_h, fb_l); MFMA16(mk0, fa_l, fb_h);
          MFMA16(ma0, fa_h, fq_h); MFMA16(ma0, fa_h, fq_l); MFMA16(ma0, fa_l, fq_h);
        } else {
          MFMA16(mk1, fa_h, fb_h); MFMA16(mk1, fa_h, fb_l); MFMA16(mk1, fa_l, fb_h);
          MFMA16(ma1, fa_h, fq_h); MFMA16(ma1, fa_h, fq_l); MFMA16(ma1, fa_l, fq_h);
        }
      }
    }
    // epilogues: sM (strict lower, beta*decay) and satt (tril, decay)
    const int r0 = mt * 16 + (lane >> 4) * 4;
    #pragma unroll
    for (int j = 0; j < 2; ++j) {
      const int scol = (tc0 + j) * 16 + (lane & 15);
      const f32x4 mkv = (j == 0) ? mk0 : mk1;
      const f32x4 mav = (j == 0) ? ma0 : ma1;
      #pragma unroll
      for (int e = 0; e < 4; ++e) {
        const int r = r0 + e;
        sM[r][scol] = (r > scol) ? mkv[e] * s_beta[r] * s_egc[r] * s_inv[scol] : 0.f;
      }
      f32x4 av;
      #pragma unroll
      for (int e = 0; e < 4; ++e) {
        const int d = r0 + e;
        av[e] = (scol >= d) ? mav[e] * s_egc[scol] * s_inv[d] : 0.f;
      }
      *(f32x4*)&satt[scol * 64 + (((r0 >> 2) ^ (scol & 3)) << 2)] = av;
    }
  }
  __syncthreads();

  if (t < 256) {
    // ---- waves 0-3: forward substitution + direct KC/VC emission ----
    float X[64];
    const int j = t;
    if (j < 128) {
      #pragma unroll
      for (int i = 0; i < 64; ++i) {
        const int go = sidx(i, j);
        X[i] = ((float)sAh[go] + (float)sAl[go]) * s_beta[i] * s_egc[i];
      }
    } else {
      const int jj = j - 128;
      #pragma unroll
      for (int i = 0; i < 64; ++i)
        X[i] = sV[i * 132 + jj] * s_beta[i];
    }
    #pragma unroll
    for (int i = 1; i < 64; ++i) {
      float s0 = 0.f, s1 = 0.f, s2 = 0.f, s3 = 0.f;
      int l = 0;
      #pragma unroll
      for (; l + 4 <= i; l += 4) {
        f32x4 m = *(const f32x4*)&sM[i][l];
        s0 += m[0] * X[l];     s1 += m[1] * X[l + 1];
        s2 += m[2] * X[l + 2]; s3 += m[3] * X[l + 3];
      }
      float s = (s0 + s2) + (s1 + s3);
      #pragma unroll
      for (; l < i; ++l) s += sM[i][l] * X[l];
      X[i] -= s;
    }
    if (j < 128) {
      _Float16* KCh = (_Float16*)(wsb + cb);
      _Float16* KCl = (_Float16*)(wsb + cb + 16384);
      #pragma unroll
      for (int c = 0; c < 64; ++c) {
        const int tile = (c >> 4) * 4 + (j >> 5);
        const int ln_  = ((j >> 3) & 3) * 16 + (c & 15);
        const int o = tile * 512 + ln_ * 8 + (j & 7);
        _Float16 h_, l_; fsplit(X[c], h_, l_);
        KCh[o] = h_; KCl[o] = l_;
      }
    } else {
      float* VC = (float*)(wsb + cb + 110592);
      const int jj = j - 128;
      #pragma unroll
      for (int a = 0; a < 16; ++a) {
        f32x4 xx;
        xx[0] = X[4*a]; xx[1] = X[4*a+1]; xx[2] = X[4*a+2]; xx[3] = X[4*a+3];
        const int eo = ((jj >> 4) * 4 + (a >> 2)) * 256 + ((a & 3) * 16 + (jj & 15)) * 4;
        *(f32x4*)&VC[eo] = xx;
      }
    }
  } else {
    // ---- waves 4-7: QG / KDT / ATT emissions ----
    const int tt = t - 256;
    // QG: A[64 c][128 dk]; val = q_norm*scale*egc[row]
    {
      _Float16* Hh = (_Float16*)(wsb + cb + 32768);
      _Float16* Ll = (_Float16*)(wsb + cb + 49152);
      #pragma unroll
      for (int i = 0; i < 8; ++i) {
        int o = i * 1024 + tt * 4;
        int tile = o >> 9, ln = (o >> 3) & 63;
        int row = (tile >> 2) * 16 + (ln & 15);
        int k0  = (tile & 3) * 32 + (ln >> 4) * 8 + (o & 7);
        const int go = sidx(row, k0);
        f16x4 qh4 = *(const f16x4*)&sQh[go];
        f16x4 ql4 = *(const f16x4*)&sQl[go];
        const float eg = s_egc[row];
        f16x4 hh, ll;
        #pragma unroll
        for (int r = 0; r < 4; ++r) {
          _Float16 h_, l_;
          fsplit(((float)qh4[r] + (float)ql4[r]) * eg, h_, l_);
          hh[r] = h_; ll[r] = l_;
        }
        *(f16x4*)(Hh + o) = hh; *(f16x4*)(Ll + o) = ll;
      }
    }
    // KDT: A[128 dk][64 c]; val = k_norm[c][dk] * ekd[c]
    {
      _Float16* Hh = (_Float16*)(wsb + cb + 65536);
      _Float16* Ll = (_Float16*)(wsb + cb + 81920);
      #pragma unroll
      for (int i = 0; i < 8; ++i) {
        int o = i * 1024 + tt * 4;
        int tile = o >> 9, ln = (o >> 3) & 63;
        int row = (tile >> 1) * 16 + (ln & 15);     // dk
        int k0  = (tile & 1) * 32 + (ln >> 4) * 8 + (o & 7);  // c
        f16x4 hh, ll;
        #pragma unroll
        for (int r = 0; r < 4; ++r) {
          const int c = k0 + r;
          const int go = sidx(c, row);
          _Float16 h_, l_;
          fsplit(((float)sAh[go] + (float)sAl[go]) * s_ekd[c], h_, l_);
          hh[r] = h_; ll[r] = l_;
        }
        *(f16x4*)(Hh + o) = hh; *(f16x4*)(Ll + o) = ll;
      }
    }
    // ATT: 6 nonzero tiles; slot s -> (mt,kt2): s<4:(s,0); 4:(2,1); 5:(3,1)
    {
      _Float16* Hh = (_Float16*)(wsb + cb + 98304);
      _Float16* Ll = (_Float16*)(wsb + cb + 104448);
      #pragma unroll
      for (int i = 0; i < 3; ++i) {
        int o = i * 1024 + tt * 4;
        int s = o >> 9, ln = (o >> 3) & 63;
        int mt  = (s < 4) ? s : (s - 2);
        int kt2 = (s < 4) ? 0 : 1;
        int row = mt * 16 + (ln & 15);
        int k0  = kt2 * 32 + (ln >> 4) * 8 + (o & 7);
        f32x4 av = *(const f32x4*)&satt[row * 64 + ((((k0 >> 2) ^ (row & 3))) << 2)];
        f16x4 hh, ll;
        #pragma unroll
        for (int r = 0; r < 4; ++r) {
          _Float16 h_, l_; fsplit(av[r], h_, l_);
          hh[r] = h_; ll[r] = l_;
        }
        *(f16x4*)(Hh + o) = hh; *(f16x4*)(Ll + o) = ll;
      }
    }
  }
}

#define VMW(N) do { asm volatile("s_waitcnt vmcnt(" #N ")" ::: "memory"); \
                    __builtin_amdgcn_sched_barrier(0); } while (0)
#define BAR() do { __builtin_amdgcn_s_barrier(); \
                   __builtin_amdgcn_sched_barrier(0); } while (0)

// per-wave 1/2 share of an nt-KB staging region (2-wave blocks)
#define STAGEW2(dst, srcB, nt) do {                                   \
    const char* s_ = (const char*)(srcB);                             \
    char* d_ = (char*)(dst);                                          \
    _Pragma("unroll")                                                 \
    for (int t_ = wave; t_ < (nt); t_ += 2)                           \
      gl_lds16(s_ + t_ * 1024 + lane * 16, d_ + t_ * 1024 + lane * 16); \
  } while (0)

__global__ __launch_bounds__(128, 1) void gdn_phaseB(
    const char* __restrict__ wsb, float* __restrict__ out,
    int bh0, long ncp, int grp)
{
  __shared__ __align__(16) _Float16 sKCh[8192], sKCl[8192];   // 32KB
  __shared__ __align__(16) _Float16 sQGh[8192], sQGl[8192];   // 32KB
  __shared__ __align__(16) _Float16 sKDh[8192], sKDl[8192];   // 32KB
  __shared__ __align__(16) _Float16 sAT[6144];                // 12KB (h|l)
  __shared__ __align__(16) _Float16 Sb[2][2][16][128];        // 16KB
  __shared__ __align__(16) _Float16 Ub[2][2][16][64];         // 8KB

  const int tid  = threadIdx.x;
  const int wave = tid >> 6;        // 0..1
  const int lane = tid & 63;
  const int jrow = lane & 15;
  const int kgrp = lane >> 4;
  const int jx3  = (jrow & 7) << 3;     // XOR swizzle for Sb/Ub cols

  const int blk    = blockIdx.x;
  const int bhl    = blk % grp;     // grp multiple of 8 -> all 4 sharers of a
  const int sharer = blk / grp;     // bh land on XCD bhl%8 (blk%8 invariant)
  const int jb     = sharer * 2 + wave;
  const int bh  = bh0 + bhl;
  const int h   = bh % Hn;
  const int b   = bh / Hn;
  const float* GLp = (const float*)(wsb + ncp * CHUNK_B);
  const char* cbase = wsb + (long)bhl * Nn * CHUNK_B;

  f32x4 S[8];
  const f32x4 zero = {0.f, 0.f, 0.f, 0.f};
  #pragma unroll
  for (int i = 0; i < 8; ++i) S[i] = zero;
  for (int i = lane; i < 2 * 16 * 128; i += 64)
    (&Sb[wave][0][0][0])[i] = (_Float16)0.f;

  // prologue: VC(0) + gl(0) regs + stage chunk 0 (KC, QG, AT) + full drain
  f32x4 vcv[4];
  {
    const float* VC0 = (const float*)(cbase + 110592);
    #pragma unroll
    for (int ct = 0; ct < 4; ++ct)
      vcv[ct] = *(const f32x4*)(VC0 + ((jb * 4 + ct) * 64 + lane) * 4);
  }
  float glc = GLp[(long)bhl * Nn];
  STAGEW2(sKCh, cbase +     0, 16); STAGEW2(sKCl, cbase + 16384, 16);
  STAGEW2(sQGh, cbase + 32768, 16); STAGEW2(sQGl, cbase + 49152, 16);
  STAGEW2(sAT,  cbase + 98304, 12);
  asm volatile("s_waitcnt vmcnt(0) lgkmcnt(0)" ::: "memory");
  __builtin_amdgcn_sched_barrier(0);
  BAR();

  float* outb = out + ((long)b * Sn) * (long)(Hn * DVn) + (long)h * DVn + jb * 16 + jrow;

  #pragma unroll 1
  for (int n = 0; n < Nn; ++n) {
    const int  np  = (n + 1 < Nn) ? n + 1 : n;
    const char* cbp = cbase + (long)n  * CHUNK_B;
    const char* cbn = cbase + (long)np * CHUNK_B;

    // ---- P0e: KC(n)+VC(n) resident (queue: KD16,VC4,KC16,QG16,AT6,ST16;
    //           retire oldest 36 = KD+VC+KC) ----
    VMW(38); BAR();
    STAGEW2(sKDh, cbp + 65536, 16); STAGEW2(sKDl, cbp + 81920, 16);  // KD(n): 16
    f32x4 vcvN[4];
    {
      const float* VCn = (const float*)(cbn + 110592);
      #pragma unroll
      for (int ct = 0; ct < 4; ++ct)
        vcvN[ct] = *(const f32x4*)(VCn + ((jb * 4 + ct) * 64 + lane) * 4);  // 4
    }
    const float glN = GLp[(long)bhl * Nn + np];   // gl(n+1), used next chunk

    // P0: state B-frags + m1
    f16x8 sbh[4], sbl[4];
    #pragma unroll
    for (int kt = 0; kt < 4; ++kt) {
      const int cx = (kt * 32 + kgrp * 8) ^ jx3;
      sbh[kt] = *(const f16x8*)&Sb[wave][0][jrow][cx];
      sbl[kt] = *(const f16x8*)&Sb[wave][1][jrow][cx];
    }
    f32x4 aA[4], aB[4], aC[4];
    #pragma unroll
    for (int i = 0; i < 4; ++i) { aA[i] = zero; aB[i] = zero; aC[i] = zero; }
    #pragma unroll
    for (int kt = 0; kt < 4; ++kt) {
      #pragma unroll
      for (int mt = 0; mt < 4; ++mt) {
        const int tl = mt * 4 + kt;
        f16x8 ah = *(const f16x8*)&sKCh[tl * 512 + lane * 8];
        f16x8 al = *(const f16x8*)&sKCl[tl * 512 + lane * 8];
        MFMA16(aA[mt], ah, sbh[kt]);
        MFMA16(aB[mt], ah, sbl[kt]);
        MFMA16(aC[mt], al, sbh[kt]);
      }
    }
    #pragma unroll
    for (int ct = 0; ct < 4; ++ct) {
      f32x4 uu = vcv[ct] - (aA[ct] + aB[ct] + aC[ct]);
      f16x4 hh, ll; _Float16 h_, l_;
      #pragma unroll
      for (int r = 0; r < 4; ++r) { fsplit(uu[r], h_, l_); hh[r] = h_; ll[r] = l_; }
      const int cu = (ct * 16 + kgrp * 4) ^ jx3;
      *(f16x4*)&Ub[wave][0][jrow][cu] = hh;
      *(f16x4*)&Ub[wave][1][jrow][cu] = ll;
    }

    // ---- P1e: QG(n) resident (queue: QG16,AT6,ST16,KD16,VC4=58; retire 16=QG) ----
    VMW(42); BAR();
    STAGEW2(sKCh, cbn +     0, 16); STAGEW2(sKCl, cbn + 16384, 16);  // 16

    // P1: m2a
    f32x4 oA[4], oB[4], oC[4];
    #pragma unroll
    for (int i = 0; i < 4; ++i) { oA[i] = zero; oB[i] = zero; oC[i] = zero; }
    #pragma unroll
    for (int kt = 0; kt < 4; ++kt) {
      #pragma unroll
      for (int mt = 0; mt < 4; ++mt) {
        const int tl = mt * 4 + kt;
        f16x8 ah = *(const f16x8*)&sQGh[tl * 512 + lane * 8];
        f16x8 al = *(const f16x8*)&sQGl[tl * 512 + lane * 8];
        MFMA16(oA[mt], ah, sbh[kt]);
        MFMA16(oB[mt], ah, sbl[kt]);
        MFMA16(oC[mt], al, sbh[kt]);
      }
    }

    // ---- P2e: AT(n) resident (queue: AT6,ST16,KD16,VC4,KC16=58; retire 6=AT;
    //           stores NOT in the dependency path) ----
    VMW(52); BAR();
    STAGEW2(sQGh, cbn + 32768, 16); STAGEW2(sQGl, cbn + 49152, 16);  // 16

    // P2: u B-frags, m2b (skip zero tiles); o4 kept in regs, stored at P3 end
    f16x8 ubh[2], ubl[2];
    #pragma unroll
    for (int kt2 = 0; kt2 < 2; ++kt2) {
      const int cx = (kt2 * 32 + kgrp * 8) ^ jx3;
      ubh[kt2] = *(const f16x8*)&Ub[wave][0][jrow][cx];
      ubl[kt2] = *(const f16x8*)&Ub[wave][1][jrow][cx];
    }
    #pragma unroll
    for (int kt2 = 0; kt2 < 2; ++kt2) {
      #pragma unroll
      for (int mt = 0; mt < 4; ++mt) {
        if (kt2 == 1 && mt < 2) continue;          // zero tiles (causal)
        const int slot = (kt2 == 0) ? mt : (mt + 2);
        f16x8 ah = *(const f16x8*)&sAT[slot * 512 + lane * 8];
        f16x8 al = *(const f16x8*)&sAT[3072 + slot * 512 + lane * 8];
        MFMA16(oA[mt], ah, ubh[kt2]);
        MFMA16(oB[mt], ah, ubl[kt2]);
        MFMA16(oC[mt], al, ubh[kt2]);
      }
    }

    // ---- P3e: KD(n) resident (queue: ST16,KD16,VC4,KC16,QG16=68;
    //           retire 32 = ST(n-1)+KD) ----
    VMW(36); BAR();
    STAGEW2(sAT, cbn + 98304, 12);                                   // 6

    // P3: m3
    #pragma unroll
    for (int i = 0; i < 8; ++i) {
      S[i][0] *= glc; S[i][1] *= glc; S[i][2] *= glc; S[i][3] *= glc;
    }
    #pragma unroll
    for (int kt2 = 0; kt2 < 2; ++kt2) {
      #pragma unroll
      for (int dt = 0; dt < 8; ++dt) {
        const int tl = dt * 2 + kt2;
        f16x8 ah = *(const f16x8*)&sKDh[tl * 512 + lane * 8];
        f16x8 al = *(const f16x8*)&sKDl[tl * 512 + lane * 8];
        MFMA16(S[dt], ah, ubh[kt2]);
        MFMA16(S[dt], ah, ubl[kt2]);
        MFMA16(S[dt], al, ubh[kt2]);
      }
    }
    // redistribute S -> Sb for next chunk
    #pragma unroll
    for (int dt = 0; dt < 8; ++dt) {
      f16x4 hh, ll; _Float16 h_, l_;
      #pragma unroll
      for (int r = 0; r < 4; ++r) { fsplit(S[dt][r], h_, l_); hh[r] = h_; ll[r] = l_; }
      const int cx = (dt * 16 + kgrp * 4) ^ jx3;
      *(f16x4*)&Sb[wave][0][jrow][cx] = hh;
      *(f16x4*)&Sb[wave][1][jrow][cx] = ll;
    }

    // out stores LAST (retire during next chunk's phases; never on a wait path)
    {
      float* orow = outb + (long)(n * 64) * (Hn * DVn);
      #pragma unroll
      for (int ct = 0; ct < 4; ++ct) {
        f32x4 o4 = oA[ct] + oB[ct] + oC[ct];
        #pragma unroll
        for (int r = 0; r < 4; ++r)
          orow[(long)(ct * 16 + kgrp * 4 + r) * (Hn * DVn)] = o4[r];   // 16
      }
    }

    #pragma unroll
    for (int ct = 0; ct < 4; ++ct) vcv[ct] = vcvN[ct];
    glc = glN;
  }
}

extern "C" void kernel_launch(void* const* d_in, const int* in_sizes, int n_in,
                              void* d_out, int out_size, void* d_ws, size_t ws_size,
                              hipStream_t stream) {
  (void)in_sizes; (void)n_in; (void)out_size;
  const float* q    = (const float*)d_in[0];
  const float* k    = (const float*)d_in[1];
  const float* v    = (const float*)d_in[2];
  const float* g    = (const float*)d_in[3];
  const float* beta = (const float*)d_in[4];
  char*  ws  = (char*)d_ws;
  float* out = (float*)d_out;

  const int NBH = Bn * Hn;                                // 32
  long fit = (long)(ws_size / (size_t)PER_BH_B);
  int G = fit >= 32 ? 32 : fit >= 24 ? 24 : fit >= 16 ? 16 : fit >= 8 ? 8
        : (int)(fit < 1 ? 1 : fit);
  const long ncp = (long)G * Nn;                          // chunk capacity/pass

  for (int bh0 = 0; bh0 < NBH; bh0 += G) {
    const int grp = (bh0 + G <= NBH) ? G : (NBH - bh0);
    hipLaunchKernelGGL(gdn_phaseA, dim3(grp * Nn), dim3(512), 0, stream,
                       q, k, v, g, beta, ws, bh0, ncp);
    hipLaunchKernelGGL(gdn_phaseB, dim3(grp * 4), dim3(128), 0, stream,
                       ws, out, bh0, ncp, grp);
  }
}

// Round 14
// 451.772 us; speedup vs baseline: 1.6801x; 1.6801x over previous
//
#include <hip/hip_runtime.h>
#include <math.h>

// Gated delta-rule linear attention (Qwen3.5 GatedDeltaNet).
// Passes split over the CHUNK axis (all 32 bh per pass): phaseB's serial scan
// cost scales with chunks/pass, so 2 chunk-passes cost ~= 1 full scan, unlike
// bh-passes (each of which paid the full 64-chunk latency chain). fp32 state
// is checkpointed in ws between passes (exact).
// Phase A (512 thr): MFMA-based M/attn (f16 h/l 3-product).
// Phase B: 4 blocks/bh x 2 waves; shared-LDS staging, 4-phase counted-vmcnt
//   pipeline; LDS-bounce C->B redistribution; stores issued last.

namespace {
constexpr int Bn = 2, Sn = 4096, Hn = 16, DKn = 128, DVn = 128, Cn = 64, Nn = 64;
constexpr int NBH = 32;
// per-chunk ws bytes: KC h/l @0/16384, QG @32768/49152, KD @65536/81920,
// AT(6 nonzero tiles) h @98304 l @104448, VC f32 @110592 (32K) => 140KB
constexpr long CHUNK_B = 143360;
}

typedef __attribute__((ext_vector_type(4))) float f32x4;
typedef __attribute__((ext_vector_type(8))) _Float16 f16x8;
typedef __attribute__((ext_vector_type(4))) _Float16 f16x4;

__device__ __forceinline__ void fsplit(float x, _Float16& h, _Float16& l) {
  h = (_Float16)x;
  l = (_Float16)(x - (float)h);
}

__device__ __forceinline__ void gl_lds16(const void* g, void* l) {
  __builtin_amdgcn_global_load_lds(
      (const __attribute__((address_space(1))) void*)g,
      (__attribute__((address_space(3))) void*)l, 16, 0, 0);
}

#define MFMA16(D, A, B) D = __builtin_amdgcn_mfma_f32_16x16x32_f16(A, B, D, 0, 0, 0)

// f16 LDS [64][128], 8-elem granules XOR-swizzled by row&7
__device__ __forceinline__ int sidx(int r, int dk) {
  return r * 128 + (((dk >> 3) ^ (r & 7)) << 3) + (dk & 7);
}

__global__ __launch_bounds__(512, 1) void gdn_phaseA(
    const float* __restrict__ q, const float* __restrict__ k,
    const float* __restrict__ v, const float* __restrict__ g,
    const float* __restrict__ beta, char* __restrict__ wsb,
    int n0, int ncpp)
{
  __shared__ __align__(16) _Float16 sAh[8192], sAl[8192];   // k norm h/l
  __shared__ __align__(16) _Float16 sQh[8192], sQl[8192];   // q norm*scale h/l
  __shared__ __align__(16) float sM[64][68];                // strict-lower M (16B rows)
  __shared__ __align__(16) float satt[4096];                // attn, swizzled
  __shared__ __align__(16) float sV[64 * 132];              // v chunk
  __shared__ float s_gc[64], s_egc[64], s_inv[64], s_ekd[64], s_beta[64];

  const int t    = threadIdx.x;
  const int lane = t & 63;
  const int w    = t >> 6;
  const int pl  = blockIdx.x;             // slot = bhl*ncpp + nl
  const int bhx = pl / ncpp;
  const int nl  = pl % ncpp;
  const int n   = n0 + nl;
  const int hh_ = bhx % Hn;
  const int bb_ = bhx / Hn;
  const long base   = (((long)bb_ * Sn + (long)n * Cn) * Hn + hh_) * DKn;
  const long rowstr = (long)Hn * DKn;                    // 2048
  const long gbase  = ((long)bb_ * Sn + (long)n * Cn) * Hn + hh_;
  const long cb     = (long)pl * CHUNK_B;
  const long gloff  = (long)NBH * ncpp * CHUNK_B;

  // ---- stage v chunk into sV (coalesced) ----
  #pragma unroll
  for (int i = 0; i < 4; ++i) {
    int idx = t + 512 * i;
    int r = idx >> 5, c4 = (idx & 31) << 2;
    *(f32x4*)&sV[r * 132 + c4] = *(const f32x4*)(v + base + (long)r * rowstr + c4);
  }

  // ---- smalls + wave-parallel scan (wave 0) ----
  if (t < 64) {
    s_beta[t] = beta[gbase + (long)t * Hn];
    float x = g[gbase + (long)t * Hn];
    #pragma unroll
    for (int s = 1; s < 64; s <<= 1) {
      float y = __shfl_up(x, s, 64);
      if (t >= s) x += y;
    }
    s_gc[t]  = x;
    float eg = expf(x);
    s_egc[t] = eg;
    s_inv[t] = expf(-x);
    float g63 = __shfl(x, 63, 64);
    s_ekd[t] = expf(g63 - x);
    if (t == 63) ((float*)(wsb + gloff))[pl] = eg;   // GL = exp(gc[63])
  }

  // ---- q/k load + l2norm (8 thr/row) + f16 split to swizzled LDS ----
  {
    const int r = t >> 3, sub = t & 7;
    f32x4 ka[4], qa[4];
    #pragma unroll
    for (int i = 0; i < 4; ++i) {
      ka[i] = *(const f32x4*)(k + base + (long)r * rowstr + sub * 16 + 4 * i);
      qa[i] = *(const f32x4*)(q + base + (long)r * rowstr + sub * 16 + 4 * i);
    }
    float sk = 0.f, sq = 0.f;
    #pragma unroll
    for (int i = 0; i < 4; ++i) {
      sk += ka[i][0]*ka[i][0] + ka[i][1]*ka[i][1] + ka[i][2]*ka[i][2] + ka[i][3]*ka[i][3];
      sq += qa[i][0]*qa[i][0] + qa[i][1]*qa[i][1] + qa[i][2]*qa[i][2] + qa[i][3]*qa[i][3];
    }
    sk += __shfl_xor(sk, 1, 64); sk += __shfl_xor(sk, 2, 64); sk += __shfl_xor(sk, 4, 64);
    sq += __shfl_xor(sq, 1, 64); sq += __shfl_xor(sq, 2, 64); sq += __shfl_xor(sq, 4, 64);
    const float rk = rsqrtf(sk + 1e-6f);
    const float rq = rsqrtf(sq + 1e-6f) * 0.08838834764831845f;  // * Dk^-0.5
    #pragma unroll
    for (int i = 0; i < 4; ++i) {
      const int dk0 = sub * 16 + 4 * i;
      const int go = sidx(r, dk0);
      f16x4 h4, l4, qh4, ql4;
      #pragma unroll
      for (int e = 0; e < 4; ++e) {
        _Float16 h_, l_;
        fsplit(ka[i][e] * rk, h_, l_); h4[e] = h_; l4[e] = l_;
        fsplit(qa[i][e] * rq, h_, l_); qh4[e] = h_; ql4[e] = l_;
      }
      *(f16x4*)&sAh[go] = h4;  *(f16x4*)&sAl[go] = l4;
      *(f16x4*)&sQh[go] = qh4; *(f16x4*)&sQl[go] = ql4;
    }
  }
  __syncthreads();

  // ---- MFMA: kkT (symmetric operand) and attT = k·qT; epilogues ----
  {
    const int mt  = w & 3;          // row-tile (r for kkT, d for att)
    const int tc0 = (w >> 2) * 2;   // col-tile base (2 tiles per wave)
    const f32x4 zero = {0.f, 0.f, 0.f, 0.f};
    f32x4 mk0 = zero, mk1 = zero, ma0 = zero, ma1 = zero;
    #pragma unroll
    for (int kt = 0; kt < 4; ++kt) {
      const int rA = mt * 16 + (lane & 15);
      const int gA = rA * 128 + (((kt * 4 + (lane >> 4)) ^ (rA & 7)) << 3);
      f16x8 fa_h = *(const f16x8*)&sAh[gA];
      f16x8 fa_l = *(const f16x8*)&sAl[gA];
      #pragma unroll
      for (int j = 0; j < 2; ++j) {
        const int rB = (tc0 + j) * 16 + (lane & 15);
        const int gB = rB * 128 + (((kt * 4 + (lane >> 4)) ^ (rB & 7)) << 3);
        f16x8 fb_h = *(const f16x8*)&sAh[gB];
        f16x8 fb_l = *(const f16x8*)&sAl[gB];
        f16x8 fq_h = *(const f16x8*)&sQh[gB];
        f16x8 fq_l = *(const f16x8*)&sQl[gB];
        if (j == 0) {
          MFMA16(mk0, fa_h, fb_h); MFMA16(mk0, fa_h, fb_l); MFMA16(mk0, fa_l, fb_h);
          MFMA16(ma0, fa_h, fq_h); MFMA16(ma0, fa_h, fq_l); MFMA16(ma0, fa_l, fq_h);
        } else {
          MFMA16(mk1, fa_h, fb_h); MFMA16(mk1, fa_h, fb_l); MFMA16(mk1, fa_l, fb_h);
          MFMA16(ma1, fa_h, fq_h); MFMA16(ma1, fa_h, fq_l); MFMA16(ma1, fa_l, fq_h);
        }
      }
    }
    // epilogues: sM (strict lower, beta*decay) and satt (tril, decay)
    const int r0 = mt * 16 + (lane >> 4) * 4;
    #pragma unroll
    for (int j = 0; j < 2; ++j) {
      const int scol = (tc0 + j) * 16 + (lane & 15);
      const f32x4 mkv = (j == 0) ? mk0 : mk1;
      const f32x4 mav = (j == 0) ? ma0 : ma1;
      #pragma unroll
      for (int e = 0; e < 4; ++e) {
        const int r = r0 + e;
        sM[r][scol] = (r > scol) ? mkv[e] * s_beta[r] * s_egc[r] * s_inv[scol] : 0.f;
      }
      f32x4 av;
      #pragma unroll
      for (int e = 0; e < 4; ++e) {
        const int d = r0 + e;
        av[e] = (scol >= d) ? mav[e] * s_egc[scol] * s_inv[d] : 0.f;
      }
      *(f32x4*)&satt[scol * 64 + (((r0 >> 2) ^ (scol & 3)) << 2)] = av;
    }
  }
  __syncthreads();

  if (t < 256) {
    // ---- waves 0-3: forward substitution + direct KC/VC emission ----
    float X[64];
    const int j = t;
    if (j < 128) {
      #pragma unroll
      for (int i = 0; i < 64; ++i) {
        const int go = sidx(i, j);
        X[i] = ((float)sAh[go] + (float)sAl[go]) * s_beta[i] * s_egc[i];
      }
    } else {
      const int jj = j - 128;
      #pragma unroll
      for (int i = 0; i < 64; ++i)
        X[i] = sV[i * 132 + jj] * s_beta[i];
    }
    #pragma unroll
    for (int i = 1; i < 64; ++i) {
      float s0 = 0.f, s1 = 0.f, s2 = 0.f, s3 = 0.f;
      int l = 0;
      #pragma unroll
      for (; l + 4 <= i; l += 4) {
        f32x4 m = *(const f32x4*)&sM[i][l];
        s0 += m[0] * X[l];     s1 += m[1] * X[l + 1];
        s2 += m[2] * X[l + 2]; s3 += m[3] * X[l + 3];
      }
      float s = (s0 + s2) + (s1 + s3);
      #pragma unroll
      for (; l < i; ++l) s += sM[i][l] * X[l];
      X[i] -= s;
    }
    if (j < 128) {
      _Float16* KCh = (_Float16*)(wsb + cb);
      _Float16* KCl = (_Float16*)(wsb + cb + 16384);
      #pragma unroll
      for (int c = 0; c < 64; ++c) {
        const int tile = (c >> 4) * 4 + (j >> 5);
        const int ln_  = ((j >> 3) & 3) * 16 + (c & 15);
        const int o = tile * 512 + ln_ * 8 + (j & 7);
        _Float16 h_, l_; fsplit(X[c], h_, l_);
        KCh[o] = h_; KCl[o] = l_;
      }
    } else {
      float* VC = (float*)(wsb + cb + 110592);
      const int jj = j - 128;
      #pragma unroll
      for (int a = 0; a < 16; ++a) {
        f32x4 xx;
        xx[0] = X[4*a]; xx[1] = X[4*a+1]; xx[2] = X[4*a+2]; xx[3] = X[4*a+3];
        const int eo = ((jj >> 4) * 4 + (a >> 2)) * 256 + ((a & 3) * 16 + (jj & 15)) * 4;
        *(f32x4*)&VC[eo] = xx;
      }
    }
  } else {
    // ---- waves 4-7: QG / KDT / ATT emissions ----
    const int tt = t - 256;
    // QG: A[64 c][128 dk]; val = q_norm*scale*egc[row]
    {
      _Float16* Hh = (_Float16*)(wsb + cb + 32768);
      _Float16* Ll = (_Float16*)(wsb + cb + 49152);
      #pragma unroll
      for (int i = 0; i < 8; ++i) {
        int o = i * 1024 + tt * 4;
        int tile = o >> 9, ln = (o >> 3) & 63;
        int row = (tile >> 2) * 16 + (ln & 15);
        int k0  = (tile & 3) * 32 + (ln >> 4) * 8 + (o & 7);
        const int go = sidx(row, k0);
        f16x4 qh4 = *(const f16x4*)&sQh[go];
        f16x4 ql4 = *(const f16x4*)&sQl[go];
        const float eg = s_egc[row];
        f16x4 hh, ll;
        #pragma unroll
        for (int r = 0; r < 4; ++r) {
          _Float16 h_, l_;
          fsplit(((float)qh4[r] + (float)ql4[r]) * eg, h_, l_);
          hh[r] = h_; ll[r] = l_;
        }
        *(f16x4*)(Hh + o) = hh; *(f16x4*)(Ll + o) = ll;
      }
    }
    // KDT: A[128 dk][64 c]; val = k_norm[c][dk] * ekd[c]
    {
      _Float16* Hh = (_Float16*)(wsb + cb + 65536);
      _Float16* Ll = (_Float16*)(wsb + cb + 81920);
      #pragma unroll
      for (int i = 0; i < 8; ++i) {
        int o = i * 1024 + tt * 4;
        int tile = o >> 9, ln = (o >> 3) & 63;
        int row = (tile >> 1) * 16 + (ln & 15);     // dk
        int k0  = (tile & 1) * 32 + (ln >> 4) * 8 + (o & 7);  // c
        f16x4 hh, ll;
        #pragma unroll
        for (int r = 0; r < 4; ++r) {
          const int c = k0 + r;
          const int go = sidx(c, row);
          _Float16 h_, l_;
          fsplit(((float)sAh[go] + (float)sAl[go]) * s_ekd[c], h_, l_);
          hh[r] = h_; ll[r] = l_;
        }
        *(f16x4*)(Hh + o) = hh; *(f16x4*)(Ll + o) = ll;
      }
    }
    // ATT: 6 nonzero tiles; slot s -> (mt,kt2): s<4:(s,0); 4:(2,1); 5:(3,1)
    {
      _Float16* Hh = (_Float16*)(wsb + cb + 98304);
      _Float16* Ll = (_Float16*)(wsb + cb + 104448);
      #pragma unroll
      for (int i = 0; i < 3; ++i) {
        int o = i * 1024 + tt * 4;
        int s = o >> 9, ln = (o >> 3) & 63;
        int mt  = (s < 4) ? s : (s - 2);
        int kt2 = (s < 4) ? 0 : 1;
        int row = mt * 16 + (ln & 15);
        int k0  = kt2 * 32 + (ln >> 4) * 8 + (o & 7);
        f32x4 av = *(const f32x4*)&satt[row * 64 + ((((k0 >> 2) ^ (row & 3))) << 2)];
        f16x4 hh, ll;
        #pragma unroll
        for (int r = 0; r < 4; ++r) {
          _Float16 h_, l_; fsplit(av[r], h_, l_);
          hh[r] = h_; ll[r] = l_;
        }
        *(f16x4*)(Hh + o) = hh; *(f16x4*)(Ll + o) = ll;
      }
    }
  }
}

#define VMW(N) do { asm volatile("s_waitcnt vmcnt(" #N ")" ::: "memory"); \
                    __builtin_amdgcn_sched_barrier(0); } while (0)
#define BAR() do { __builtin_amdgcn_s_barrier(); \
                   __builtin_amdgcn_sched_barrier(0); } while (0)

// per-wave 1/2 share of an nt-KB staging region (2-wave blocks)
#define STAGEW2(dst, srcB, nt) do {                                   \
    const char* s_ = (const char*)(srcB);                             \
    char* d_ = (char*)(dst);                                          \
    _Pragma("unroll")                                                 \
    for (int t_ = wave; t_ < (nt); t_ += 2)                           \
      gl_lds16(s_ + t_ * 1024 + lane * 16, d_ + t_ * 1024 + lane * 16); \
  } while (0)

__global__ __launch_bounds__(128, 1) void gdn_phaseB(
    char* __restrict__ wsb, float* __restrict__ out,
    int n0, int ncpp, int lastpass)
{
  __shared__ __align__(16) _Float16 sKCh[8192], sKCl[8192];   // 32KB
  __shared__ __align__(16) _Float16 sQGh[8192], sQGl[8192];   // 32KB
  __shared__ __align__(16) _Float16 sKDh[8192], sKDl[8192];   // 32KB
  __shared__ __align__(16) _Float16 sAT[6144];                // 12KB (h|l)
  __shared__ __align__(16) _Float16 Sb[2][2][16][128];        // 16KB
  __shared__ __align__(16) _Float16 Ub[2][2][16][64];         // 8KB

  const int tid  = threadIdx.x;
  const int wave = tid >> 6;        // 0..1
  const int lane = tid & 63;
  const int jrow = lane & 15;
  const int kgrp = lane >> 4;
  const int jx3  = (jrow & 7) << 3;     // XOR swizzle for Sb/Ub cols

  const int blk    = blockIdx.x;
  const int bhl    = blk & 31;      // sharers (blk, +32, +64, +96): same XCD
  const int sharer = blk >> 5;
  const int jb     = sharer * 2 + wave;
  const int h   = bhl % Hn;
  const int b   = bhl / Hn;
  const long gloff = (long)NBH * ncpp * CHUNK_B;
  const float* GLp = (const float*)(wsb + gloff);
  float* STp = (float*)(wsb + gloff + 32768) + (((long)bhl * 8 + jb) * 64 + lane) * 32;
  const char* cbase = wsb + (long)bhl * ncpp * CHUNK_B;

  f32x4 S[8];
  const f32x4 zero = {0.f, 0.f, 0.f, 0.f};
  if (n0 == 0) {
    #pragma unroll
    for (int i = 0; i < 8; ++i) S[i] = zero;
  } else {
    #pragma unroll
    for (int i = 0; i < 8; ++i) S[i] = *(const f32x4*)(STp + i * 4);
  }
  // Sb init from S (redistribute; zeros on pass 0)
  #pragma unroll
  for (int dt = 0; dt < 8; ++dt) {
    f16x4 hh, ll; _Float16 h_, l_;
    #pragma unroll
    for (int r = 0; r < 4; ++r) { fsplit(S[dt][r], h_, l_); hh[r] = h_; ll[r] = l_; }
    const int cx = (dt * 16 + kgrp * 4) ^ jx3;
    *(f16x4*)&Sb[wave][0][jrow][cx] = hh;
    *(f16x4*)&Sb[wave][1][jrow][cx] = ll;
  }

  // prologue: VC(0) + gl(0) regs + stage chunk 0 (KC, QG, AT) + full drain
  f32x4 vcv[4];
  {
    const float* VC0 = (const float*)(cbase + 110592);
    #pragma unroll
    for (int ct = 0; ct < 4; ++ct)
      vcv[ct] = *(const f32x4*)(VC0 + ((jb * 4 + ct) * 64 + lane) * 4);
  }
  float glc = GLp[(long)bhl * ncpp];
  STAGEW2(sKCh, cbase +     0, 16); STAGEW2(sKCl, cbase + 16384, 16);
  STAGEW2(sQGh, cbase + 32768, 16); STAGEW2(sQGl, cbase + 49152, 16);
  STAGEW2(sAT,  cbase + 98304, 12);
  asm volatile("s_waitcnt vmcnt(0) lgkmcnt(0)" ::: "memory");
  __builtin_amdgcn_sched_barrier(0);
  BAR();

  float* outb = out + ((long)b * Sn) * (long)(Hn * DVn) + (long)h * DVn + jb * 16 + jrow;

  #pragma unroll 1
  for (int nl = 0; nl < ncpp; ++nl) {
    const int  np  = (nl + 1 < ncpp) ? nl + 1 : nl;
    const char* cbp = cbase + (long)nl * CHUNK_B;
    const char* cbn = cbase + (long)np * CHUNK_B;
    const int n = n0 + nl;

    // ---- P0e: KC(n)+VC(n) resident ----
    VMW(38); BAR();
    STAGEW2(sKDh, cbp + 65536, 16); STAGEW2(sKDl, cbp + 81920, 16);  // KD(n): 16
    f32x4 vcvN[4];
    {
      const float* VCn = (const float*)(cbn + 110592);
      #pragma unroll
      for (int ct = 0; ct < 4; ++ct)
        vcvN[ct] = *(const f32x4*)(VCn + ((jb * 4 + ct) * 64 + lane) * 4);  // 4
    }
    const float glN = GLp[(long)bhl * ncpp + np];

    // P0: state B-frags + m1
    f16x8 sbh[4], sbl[4];
    #pragma unroll
    for (int kt = 0; kt < 4; ++kt) {
      const int cx = (kt * 32 + kgrp * 8) ^ jx3;
      sbh[kt] = *(const f16x8*)&Sb[wave][0][jrow][cx];
      sbl[kt] = *(const f16x8*)&Sb[wave][1][jrow][cx];
    }
    f32x4 aA[4], aB[4], aC[4];
    #pragma unroll
    for (int i = 0; i < 4; ++i) { aA[i] = zero; aB[i] = zero; aC[i] = zero; }
    #pragma unroll
    for (int kt = 0; kt < 4; ++kt) {
      #pragma unroll
      for (int mt = 0; mt < 4; ++mt) {
        const int tl = mt * 4 + kt;
        f16x8 ah = *(const f16x8*)&sKCh[tl * 512 + lane * 8];
        f16x8 al = *(const f16x8*)&sKCl[tl * 512 + lane * 8];
        MFMA16(aA[mt], ah, sbh[kt]);
        MFMA16(aB[mt], ah, sbl[kt]);
        MFMA16(aC[mt], al, sbh[kt]);
      }
    }
    #pragma unroll
    for (int ct = 0; ct < 4; ++ct) {
      f32x4 uu = vcv[ct] - (aA[ct] + aB[ct] + aC[ct]);
      f16x4 hh, ll; _Float16 h_, l_;
      #pragma unroll
      for (int r = 0; r < 4; ++r) { fsplit(uu[r], h_, l_); hh[r] = h_; ll[r] = l_; }
      const int cu = (ct * 16 + kgrp * 4) ^ jx3;
      *(f16x4*)&Ub[wave][0][jrow][cu] = hh;
      *(f16x4*)&Ub[wave][1][jrow][cu] = ll;
    }

    // ---- P1e: QG(n) resident ----
    VMW(42); BAR();
    STAGEW2(sKCh, cbn +     0, 16); STAGEW2(sKCl, cbn + 16384, 16);  // 16

    // P1: m2a
    f32x4 oA[4], oB[4], oC[4];
    #pragma unroll
    for (int i = 0; i < 4; ++i) { oA[i] = zero; oB[i] = zero; oC[i] = zero; }
    #pragma unroll
    for (int kt = 0; kt < 4; ++kt) {
      #pragma unroll
      for (int mt = 0; mt < 4; ++mt) {
        const int tl = mt * 4 + kt;
        f16x8 ah = *(const f16x8*)&sQGh[tl * 512 + lane * 8];
        f16x8 al = *(const f16x8*)&sQGl[tl * 512 + lane * 8];
        MFMA16(oA[mt], ah, sbh[kt]);
        MFMA16(oB[mt], ah, sbl[kt]);
        MFMA16(oC[mt], al, sbh[kt]);
      }
    }

    // ---- P2e: AT(n) resident ----
    VMW(52); BAR();
    STAGEW2(sQGh, cbn + 32768, 16); STAGEW2(sQGl, cbn + 49152, 16);  // 16

    // P2: u B-frags, m2b (skip zero tiles); o4 stored at chunk end
    f16x8 ubh[2], ubl[2];
    #pragma unroll
    for (int kt2 = 0; kt2 < 2; ++kt2) {
      const int cx = (kt2 * 32 + kgrp * 8) ^ jx3;
      ubh[kt2] = *(const f16x8*)&Ub[wave][0][jrow][cx];
      ubl[kt2] = *(const f16x8*)&Ub[wave][1][jrow][cx];
    }
    #pragma unroll
    for (int kt2 = 0; kt2 < 2; ++kt2) {
      #pragma unroll
      for (int mt = 0; mt < 4; ++mt) {
        if (kt2 == 1 && mt < 2) continue;          // zero tiles (causal)
        const int slot = (kt2 == 0) ? mt : (mt + 2);
        f16x8 ah = *(const f16x8*)&sAT[slot * 512 + lane * 8];
        f16x8 al = *(const f16x8*)&sAT[3072 + slot * 512 + lane * 8];
        MFMA16(oA[mt], ah, ubh[kt2]);
        MFMA16(oB[mt], ah, ubl[kt2]);
        MFMA16(oC[mt], al, ubh[kt2]);
      }
    }

    // ---- P3e: KD(n) resident ----
    VMW(36); BAR();
    STAGEW2(sAT, cbn + 98304, 12);                                   // 6

    // P3: m3
    #pragma unroll
    for (int i = 0; i < 8; ++i) {
      S[i][0] *= glc; S[i][1] *= glc; S[i][2] *= glc; S[i][3] *= glc;
    }
    #pragma unroll
    for (int kt2 = 0; kt2 < 2; ++kt2) {
      #pragma unroll
      for (int dt = 0; dt < 8; ++dt) {
        const int tl = dt * 2 + kt2;
        f16x8 ah = *(const f16x8*)&sKDh[tl * 512 + lane * 8];
        f16x8 al = *(const f16x8*)&sKDl[tl * 512 + lane * 8];
        MFMA16(S[dt], ah, ubh[kt2]);
        MFMA16(S[dt], ah, ubl[kt2]);
        MFMA16(S[dt], al, ubh[kt2]);
      }
    }
    // redistribute S -> Sb for next chunk
    #pragma unroll
    for (int dt = 0; dt < 8; ++dt) {
      f16x4 hh, ll; _Float16 h_, l_;
      #pragma unroll
      for (int r = 0; r < 4; ++r) { fsplit(S[dt][r], h_, l_); hh[r] = h_; ll[r] = l_; }
      const int cx = (dt * 16 + kgrp * 4) ^ jx3;
      *(f16x4*)&Sb[wave][0][jrow][cx] = hh;
      *(f16x4*)&Sb[wave][1][jrow][cx] = ll;
    }

    // out stores LAST (never on a wait path)
    {
      float* orow = outb + (long)(n * 64) * (Hn * DVn);
      #pragma unroll
      for (int ct = 0; ct < 4; ++ct) {
        f32x4 o4 = oA[ct] + oB[ct] + oC[ct];
        #pragma unroll
        for (int r = 0; r < 4; ++r)
          orow[(long)(ct * 16 + kgrp * 4 + r) * (Hn * DVn)] = o4[r];   // 16
      }
    }

    #pragma unroll
    for (int ct = 0; ct < 4; ++ct) vcv[ct] = vcvN[ct];
    glc = glN;
  }

  // checkpoint state for the next chunk-pass (exact fp32)
  if (!lastpass) {
    #pragma unroll
    for (int i = 0; i < 8; ++i) *(f32x4*)(STp + i * 4) = S[i];
  }
}

extern "C" void kernel_launch(void* const* d_in, const int* in_sizes, int n_in,
                              void* d_out, int out_size, void* d_ws, size_t ws_size,
                              hipStream_t stream) {
  (void)in_sizes; (void)n_in; (void)out_size;
  const float* q    = (const float*)d_in[0];
  const float* k    = (const float*)d_in[1];
  const float* v    = (const float*)d_in[2];
  const float* g    = (const float*)d_in[3];
  const float* beta = (const float*)d_in[4];
  char*  ws  = (char*)d_ws;
  float* out = (float*)d_out;

  // largest chunks-per-pass (divisor of 64) whose arrays + GL + state fit
  int NCP = 8;
  for (int c = 64; c >= 8; c >>= 1) {
    long need = (long)NBH * c * CHUNK_B + 32768 + 2097152;
    if ((size_t)need <= ws_size) { NCP = c; break; }
  }

  for (int n0 = 0; n0 < Nn; n0 += NCP) {
    const int last = (n0 + NCP >= Nn) ? 1 : 0;
    hipLaunchKernelGGL(gdn_phaseA, dim3(NBH * NCP), dim3(512), 0, stream,
                       q, k, v, g, beta, ws, n0, NCP);
    hipLaunchKernelGGL(gdn_phaseB, dim3(128), dim3(128), 0, stream,
                       ws, out, n0, NCP, last);
  }
}